// Round 4
// baseline (552.269 us; speedup 1.0000x reference)
//
#include <hip/hip_runtime.h>
#include <hip/hip_fp16.h>

#define HS 1024
#define TT 2048

typedef _Float16 half8 __attribute__((ext_vector_type(8)));
typedef float floatx4 __attribute__((ext_vector_type(4)));

// Async global->LDS DMA, 16B per lane. LDS dest = wave-uniform base + lane*16.
__device__ __forceinline__ void dma16(const _Float16* g, _Float16* l) {
    __builtin_amdgcn_global_load_lds(
        (const __attribute__((address_space(1))) unsigned int*)g,
        (__attribute__((address_space(3))) unsigned int*)l, 16, 0, 0);
}

// ---------------- fused pre-pass ---------------------------------------------
// block ranges: [0,16384) cvtA (4-row granularity len skip), [16384,24576)
// dproj, [24576,25600) cvtW, [25600,25664) zero sc, [25664,25696) zero ctx,
// [25696,25760) build row table: tbl[v] = n*TT + t for the v-th valid row in
// n-major concatenation of the first len[n] rows of each n; -1 for v >= S.
__global__ __launch_bounds__(256) void k_pre(const float* __restrict__ h_enc,
                                             _Float16* __restrict__ h_enc16,
                                             const float* __restrict__ h_dec,
                                             const float* __restrict__ W,
                                             const float* __restrict__ bias,
                                             const int* __restrict__ lens,
                                             float* __restrict__ dproj,
                                             _Float16* __restrict__ We16,
                                             float* __restrict__ sc,
                                             float* __restrict__ ctx,
                                             int* __restrict__ tbl) {
    const int b = blockIdx.x;
    const int tid = threadIdx.x;
    if (b < 16384) {
        // cvtA: block covers 4 t-rows of one n; only rows t < len are needed
        // (k_score reads only table rows, k_ctxsm clamps to len).
        const int n = b >> 9;
        const int t4 = (b & 511) * 4;
        if (t4 >= lens[n]) return;
        size_t idx = ((size_t)b * 256 + tid) * 16;
        const float4* g = reinterpret_cast<const float4*>(h_enc + idx);
        _Float16 h[16];
#pragma unroll
        for (int i = 0; i < 4; ++i) {
            float4 f = g[i];
            h[i * 4 + 0] = (_Float16)f.x; h[i * 4 + 1] = (_Float16)f.y;
            h[i * 4 + 2] = (_Float16)f.z; h[i * 4 + 3] = (_Float16)f.w;
        }
        *reinterpret_cast<uint4*>(h_enc16 + idx)     = *reinterpret_cast<uint4*>(&h[0]);
        *reinterpret_cast<uint4*>(h_enc16 + idx + 8) = *reinterpret_cast<uint4*>(&h[8]);
    } else if (b < 24576) {
        // dproj: one wave per (n,a)
        int wid = (b - 16384) * 4 + (tid >> 6);
        int lane = tid & 63;
        int n = wid >> 10, a = wid & 1023;
        const float4* hd = reinterpret_cast<const float4*>(h_dec + (size_t)n * HS);
        const float4* wr = reinterpret_cast<const float4*>(W + (size_t)a * 2048);
        float s = 0.f;
#pragma unroll
        for (int i = 0; i < 4; ++i) {
            float4 h = hd[lane + i * 64];
            float4 w = wr[lane + i * 64];
            s += h.x * w.x + h.y * w.y + h.z * w.z + h.w * w.w;
        }
        for (int off = 32; off; off >>= 1) s += __shfl_xor(s, off);
        if (lane == 0) dproj[wid] = bias[a] + s;
    } else if (b < 25600) {
        // cvtW: We16[a*1024+e] = (fp16) W[a*2048 + 1024 + e]
        int idx4 = ((b - 24576) * 256 + tid) * 4;
        int a = idx4 >> 10;
        int e = idx4 & 1023;
        float4 f = *reinterpret_cast<const float4*>(W + (size_t)a * 2048 + 1024 + e);
        _Float16 h0 = (_Float16)f.x, h1 = (_Float16)f.y, h2 = (_Float16)f.z, h3 = (_Float16)f.w;
        ushort4 p;
        p.x = *(unsigned short*)&h0; p.y = *(unsigned short*)&h1;
        p.z = *(unsigned short*)&h2; p.w = *(unsigned short*)&h3;
        *reinterpret_cast<ushort4*>(We16 + idx4) = p;
    } else if (b < 25664) {
        reinterpret_cast<float4*>(sc)[(b - 25600) * 256 + tid] =
            make_float4(0.f, 0.f, 0.f, 0.f);
    } else if (b < 25696) {
        reinterpret_cast<float4*>(ctx)[(b - 25664) * 256 + tid] =
            make_float4(0.f, 0.f, 0.f, 0.f);
    } else {
        // row table build: 64 blocks x 256 threads x 4 entries = 65536
        const int bi = b - 25696;
        const int v0 = bi * 1024 + tid * 4;
        int vals[4] = {-1, -1, -1, -1};
        int base = 0;
        for (int n = 0; n < 32; ++n) {
            const int ln = lens[n];
#pragma unroll
            for (int k2 = 0; k2 < 4; ++k2) {
                const int vv = v0 + k2;
                if (vv >= base && vv < base + ln) vals[k2] = n * TT + (vv - base);
            }
            base += ln;
        }
        *reinterpret_cast<int4*>(tbl + v0) = make_int4(vals[0], vals[1], vals[2], vals[3]);
    }
}

// K3: flattened fused score GEMM. Virtual-row M dimension (length S = sum(len))
// tiled 128t x 128a, full K=1024 per item (tanh epilogue needs complete dots).
// 256 thr = 4 waves (2m x 2n), wave 64x64, acc 4x4. LDS: ring-3 of BK=32
// K-tiles (A 8KB + B 8KB each) = 48.5 KB -> 3 blocks/CU = 12 waves/CU.
// Per-lane DMA source addressing resolves each row's (n,t) via tbl gather.
// Counted vmcnt(4): stage(j+1) stays in flight across the per-tile barrier.
// Ring-3 safety: stage(j+2) targets buf (j+2)%3 = (j-1)%3, whose reads all
// completed before this iteration's top barrier. Swizzle identical to r1
// (verified 0-conflict): granule G -> G ^ ((G>>3)&7), applied on pre-swizzled
// global source (linear LDS dest) and on ds_read byte offsets.
__global__ __launch_bounds__(256, 3) void k_score8(
        const _Float16* __restrict__ h_enc16, const _Float16* __restrict__ We16,
        const float* __restrict__ dproj, const float* __restrict__ v,
        const int* __restrict__ lens, const int* __restrict__ tbl,
        float* __restrict__ scores) {
    __shared__ _Float16 As[3][128 * 32];   // 3 x 8 KB
    __shared__ _Float16 Bs[3][128 * 32];   // 3 x 8 KB
    __shared__ float s_acc[128];

    const int tid = threadIdx.x;
    const int lane = tid & 63;

    // S = sum(lens): 32 lanes load, 64-lane xor-reduce (uniform across waves)
    int S = (lane < 32) ? lens[lane] : 0;
#pragma unroll
    for (int off = 1; off <= 32; off <<= 1) S += __shfl_xor(S, off);
    const int Tt = (S + 127) >> 7;         // tiles over virtual rows

    // XCD swizzle (4096 = 8 x 512, bijective): consecutive ords (sharing an
    // A-tile across the 8 aT) land on one XCD's L2.
    const int ord = ((blockIdx.x & 7) << 9) | (blockIdx.x >> 3);
    const int aT = ord & 7, tile = ord >> 3;
    if (tile >= Tt) return;                // beyond work list: exit
    const int t0 = tile << 7, a0 = aT << 7;

    if (tid < 128) s_acc[tid] = 0.0f;

    const int w = tid >> 6;
    const int wm = w >> 1, wn = w & 1;     // 2x2 wave grid, wave 64t x 64a
    const int col = lane & 15, quad = lane >> 4;

    // Staging source map: phys granule Gp = c*256+tid (linear LDS dest);
    // logical Gl = Gp ^ ((Gp>>3)&7); row r = Gl>>2 (0..127), granule g = Gl&3.
    // A's global row comes from the flattening table (pads clamp to row 0).
    const _Float16* srcA[2];
    const _Float16* srcB[2];
#pragma unroll
    for (int c = 0; c < 2; ++c) {
        int Gp = c * 256 + tid;
        int Gl = Gp ^ ((Gp >> 3) & 7);
        int r = Gl >> 2, g = Gl & 3;
        int grow = tbl[t0 + r];
        if (grow < 0) grow = 0;
        srcA[c] = h_enc16 + (size_t)grow * HS + g * 8;
        srcB[c] = We16 + ((size_t)(a0 + r)) * HS + g * 8;
    }

    // Pre-swizzled ds_read byte offsets (same involution as the source side).
    int offA[4], offB[4];
#pragma unroll
    for (int mi = 0; mi < 4; ++mi) {
        int r = wm * 64 + mi * 16 + col;
        offA[mi] = (r * 64 + quad * 16) ^ (((r >> 1) & 7) << 4);
    }
#pragma unroll
    for (int ni = 0; ni < 4; ++ni) {
        int r = wn * 64 + ni * 16 + col;
        offB[ni] = (r * 64 + quad * 16) ^ (((r >> 1) & 7) << 4);
    }

    floatx4 acc[4][4];
#pragma unroll
    for (int mi = 0; mi < 4; ++mi)
#pragma unroll
        for (int ni = 0; ni < 4; ++ni) acc[mi][ni] = (floatx4)0.0f;

    auto issue = [&](int kt) {
        const int bb = kt % 3;
#pragma unroll
        for (int c = 0; c < 2; ++c) {
            dma16(srcA[c] + kt * 32, &As[bb][(c * 256 + w * 64) * 8]);
            dma16(srcB[c] + kt * 32, &Bs[bb][(c * 256 + w * 64) * 8]);
        }
    };

    issue(0);
    issue(1);            // 8 loads/thread in flight

    for (int j = 0; j < 31; ++j) {
        // tile j landed when only stage(j+1)'s 4 loads remain outstanding
        asm volatile("s_waitcnt vmcnt(4)" ::: "memory");
        __builtin_amdgcn_s_barrier();
        __builtin_amdgcn_sched_barrier(0);

        const int bb = j % 3;
        const char* Ab = (const char*)As[bb];
        const char* Bb = (const char*)Bs[bb];
        half8 af[4], bf[4];
#pragma unroll
        for (int mi = 0; mi < 4; ++mi)
            af[mi] = *reinterpret_cast<const half8*>(Ab + offA[mi]);
#pragma unroll
        for (int ni = 0; ni < 4; ++ni)
            bf[ni] = *reinterpret_cast<const half8*>(Bb + offB[ni]);
        if (j < 30) issue(j + 2);   // buf (j+2)%3 = (j-1)%3, freed at barrier
        __builtin_amdgcn_s_setprio(1);
#pragma unroll
        for (int mi = 0; mi < 4; ++mi)
#pragma unroll
            for (int ni = 0; ni < 4; ++ni)
                acc[mi][ni] = __builtin_amdgcn_mfma_f32_16x16x32_f16(
                    af[mi], bf[ni], acc[mi][ni], 0, 0, 0);
        __builtin_amdgcn_s_setprio(0);
    }
    {   // final K-tile j = 31
        asm volatile("s_waitcnt vmcnt(0)" ::: "memory");
        __builtin_amdgcn_s_barrier();
        __builtin_amdgcn_sched_barrier(0);
        const char* Ab = (const char*)As[31 % 3];
        const char* Bb = (const char*)Bs[31 % 3];
        half8 af[4], bf[4];
#pragma unroll
        for (int mi = 0; mi < 4; ++mi)
            af[mi] = *reinterpret_cast<const half8*>(Ab + offA[mi]);
#pragma unroll
        for (int ni = 0; ni < 4; ++ni)
            bf[ni] = *reinterpret_cast<const half8*>(Bb + offB[ni]);
        __builtin_amdgcn_s_setprio(1);
#pragma unroll
        for (int mi = 0; mi < 4; ++mi)
#pragma unroll
            for (int ni = 0; ni < 4; ++ni)
                acc[mi][ni] = __builtin_amdgcn_mfma_f32_16x16x32_f16(
                    af[mi], bf[ni], acc[mi][ni], 0, 0, 0);
        __builtin_amdgcn_s_setprio(0);
    }

    // epilogue: s_acc[t] += sum_a v[a]*tanh(C[t][a] + dproj[n(t),a]).
    // C/D layout: col = lane&15 (a), row = quad*4+reg (t). n per row via tbl.
    float vv[4];
#pragma unroll
    for (int ni = 0; ni < 4; ++ni) vv[ni] = v[a0 + wn * 64 + ni * 16 + col];
#pragma unroll
    for (int mi = 0; mi < 4; ++mi) {
#pragma unroll
        for (int rg = 0; rg < 4; ++rg) {
            const int rloc = wm * 64 + mi * 16 + quad * 4 + rg;
            const int rv = tbl[t0 + rloc];
            const int n0 = (rv < 0) ? 0 : (rv >> 11);      // rv = n*2048 + t
            const float* dp = dproj + (size_t)n0 * HS + a0 + wn * 64 + col;
            float s = 0.0f;
#pragma unroll
            for (int ni = 0; ni < 4; ++ni) {
                float x = acc[mi][ni][rg] + dp[ni * 16];
                float e2 = __expf(2.0f * x);
                float th = 1.0f - 2.0f * __builtin_amdgcn_rcpf(e2 + 1.0f);
                s += vv[ni] * th;
            }
            s += __shfl_xor(s, 8);
            s += __shfl_xor(s, 4);
            s += __shfl_xor(s, 2);
            s += __shfl_xor(s, 1);
            if (col == 0) atomicAdd(&s_acc[rloc], s);
        }
    }
    __syncthreads();
    if (tid < 128) {
        const int rv = tbl[t0 + tid];
        if (rv >= 0) atomicAdd(&scores[rv], s_acc[tid]);   // sc pre-zeroed
    }
}

// ---------------- fused softmax + weights write + ctx accumulate -------------
// 512 blocks: n(32) x ec(4) x ts(4). Each block recomputes its row's masked
// (m, sum) from scores (L2-hot); ec==0 blocks write the weights chunk;
// ctx partial accumulated only over t < len.
__global__ __launch_bounds__(256) void k_ctxsm(const _Float16* __restrict__ h_enc16,
                                               const float* __restrict__ sc,
                                               const int* __restrict__ lens,
                                               float* __restrict__ wts,
                                               float* __restrict__ ctx) {
    __shared__ float red[4], red2[4];
    __shared__ float racc[256][8];
    const int b = blockIdx.x;
    const int n = b >> 4, ec = (b >> 2) & 3, ts = b & 3;
    const int tid = threadIdx.x;
    const int len = lens[n];
    const float* srow = sc + (size_t)n * TT;

    float sv[8];
    float m = -3.0e38f;
#pragma unroll
    for (int i = 0; i < 8; ++i) {
        int t = tid + i * 256;
        float s = srow[t];
        s = (t < len) ? s : -1.0e10f;
        sv[i] = s;
        m = fmaxf(m, s);
    }
    for (int off = 1; off <= 32; off <<= 1) m = fmaxf(m, __shfl_xor(m, off));
    if ((tid & 63) == 0) red[tid >> 6] = m;
    __syncthreads();
    m = fmaxf(fmaxf(red[0], red[1]), fmaxf(red[2], red[3]));
    float sum = 0.f;
#pragma unroll
    for (int i = 0; i < 8; ++i) sum += __expf(sv[i] - m);
    for (int off = 1; off <= 32; off <<= 1) sum += __shfl_xor(sum, off);
    if ((tid & 63) == 0) red2[tid >> 6] = sum;
    __syncthreads();
    sum = red2[0] + red2[1] + red2[2] + red2[3];
    const float rinv = 1.0f / sum;

    if (ec == 0) {
#pragma unroll
        for (int j = 0; j < 2; ++j) {
            int t = ts * 512 + j * 256 + tid;
            float s = srow[t];
            s = (t < len) ? s : -1.0e10f;
            wts[(size_t)n * TT + t] = __expf(s - m) * rinv;   // masked -> 0.f
        }
    }

    if (ts * 512 < len) {
        const int tend = min(ts * 512 + 512, len);
        const int q = tid & 31, tg = tid >> 5;
        const int e = ec * 256 + q * 8;
        float acc[8];
#pragma unroll
        for (int j = 0; j < 8; ++j) acc[j] = 0.f;
        for (int t = ts * 512 + tg; t < tend; t += 8) {
            float w = __expf(srow[t] - m) * rinv;
            uint4 raw = *reinterpret_cast<const uint4*>(
                h_enc16 + ((size_t)(n * TT + t)) * HS + e);
            const _Float16* hp = reinterpret_cast<const _Float16*>(&raw);
#pragma unroll
            for (int j = 0; j < 8; ++j) acc[j] += w * (float)hp[j];
        }
#pragma unroll
        for (int j = 0; j < 8; ++j) racc[tid][j] = acc[j];
        __syncthreads();
        if (tid < 32) {
            float s2[8];
#pragma unroll
            for (int j = 0; j < 8; ++j) s2[j] = racc[tid][j];
            for (int g = 1; g < 8; ++g)
#pragma unroll
                for (int j = 0; j < 8; ++j) s2[j] += racc[g * 32 + tid][j];
            float* dst = ctx + (size_t)n * HS + ec * 256 + tid * 8;
#pragma unroll
            for (int j = 0; j < 8; ++j) atomicAdd(dst + j, s2[j]);
        }
    }
}

// ---------- slow-but-correct fallback (only if ws is tiny; unexpected) -------
__global__ __launch_bounds__(256) void k_dproj(const float* __restrict__ h_dec,
                                               const float* __restrict__ W,
                                               const float* __restrict__ bias,
                                               float* __restrict__ dproj) {
    int wid = blockIdx.x * 4 + (threadIdx.x >> 6);
    int lane = threadIdx.x & 63;
    int n = wid >> 10, a = wid & 1023;
    const float4* hd = reinterpret_cast<const float4*>(h_dec + (size_t)n * HS);
    const float4* wr = reinterpret_cast<const float4*>(W + (size_t)a * 2048);
    float s = 0.f;
#pragma unroll
    for (int i = 0; i < 4; ++i) {
        float4 h = hd[lane + i * 64];
        float4 w = wr[lane + i * 64];
        s += h.x * w.x + h.y * w.y + h.z * w.z + h.w * w.w;
    }
    for (int off = 32; off; off >>= 1) s += __shfl_xor(s, off);
    if (lane == 0) dproj[wid] = bias[a] + s;
}

__global__ __launch_bounds__(256) void k_score_naive(const float* __restrict__ h_enc,
                                                     const float* __restrict__ W,
                                                     const float* __restrict__ dproj,
                                                     const float* __restrict__ v,
                                                     float* __restrict__ scores) {
    int gw = blockIdx.x * 4 + (threadIdx.x >> 6);
    int lane = threadIdx.x & 63;
    int n = gw >> 11, t = gw & 2047;
    const float4* he = reinterpret_cast<const float4*>(h_enc + ((size_t)(n * TT + t)) * HS);
    float4 hv[4];
#pragma unroll
    for (int i = 0; i < 4; ++i) hv[i] = he[lane + i * 64];
    float s = 0.f;
    for (int a = 0; a < 1024; ++a) {
        const float4* wr = reinterpret_cast<const float4*>(W + (size_t)a * 2048 + 1024);
        float d = 0.f;
#pragma unroll
        for (int i = 0; i < 4; ++i) {
            float4 wv = wr[lane + i * 64];
            d += hv[i].x * wv.x + hv[i].y * wv.y + hv[i].z * wv.z + hv[i].w * wv.w;
        }
        for (int off = 32; off; off >>= 1) d += __shfl_xor(d, off);
        s += v[a] * tanhf(d + dproj[n * HS + a]);
    }
    if (lane == 0) scores[(size_t)n * TT + t] = s;
}

__global__ __launch_bounds__(256) void k_softmax(float* __restrict__ wout,
                                                 const int* __restrict__ lens) {
    __shared__ float red[4];
    __shared__ float red2[4];
    int n = blockIdx.x, tid = threadIdx.x;
    int len = lens[n];
    float* row = wout + (size_t)n * TT;
    float sv[8];
    float m = -3.0e38f;
#pragma unroll
    for (int i = 0; i < 8; ++i) {
        int t = tid + i * 256;
        float s = row[t];
        s = (t < len) ? s : -1.0e10f;
        sv[i] = s;
        m = fmaxf(m, s);
    }
    for (int off = 1; off <= 32; off <<= 1) m = fmaxf(m, __shfl_xor(m, off));
    if ((tid & 63) == 0) red[tid >> 6] = m;
    __syncthreads();
    m = fmaxf(fmaxf(red[0], red[1]), fmaxf(red[2], red[3]));
    float sum = 0.f, es[8];
#pragma unroll
    for (int i = 0; i < 8; ++i) { es[i] = __expf(sv[i] - m); sum += es[i]; }
    for (int off = 1; off <= 32; off <<= 1) sum += __shfl_xor(sum, off);
    if ((tid & 63) == 0) red2[tid >> 6] = sum;
    __syncthreads();
    sum = red2[0] + red2[1] + red2[2] + red2[3];
    float rinv = 1.0f / sum;
#pragma unroll
    for (int i = 0; i < 8; ++i) row[tid + i * 256] = es[i] * rinv;
}

__global__ __launch_bounds__(256) void k_ctx_naive(const float* __restrict__ h_enc,
                                                   const float* __restrict__ wts,
                                                   float* __restrict__ ctx) {
    int n = blockIdx.x;
    int e = threadIdx.x * 4;
    float4 a = make_float4(0.f, 0.f, 0.f, 0.f);
    const float* wrow = wts + (size_t)n * TT;
    for (int t = 0; t < TT; ++t) {
        float w = wrow[t];
        float4 h = *reinterpret_cast<const float4*>(h_enc + ((size_t)(n * TT + t)) * HS + e);
        a.x += w * h.x; a.y += w * h.y; a.z += w * h.z; a.w += w * h.w;
    }
    *reinterpret_cast<float4*>(ctx + (size_t)n * HS + e) = a;
}

extern "C" void kernel_launch(void* const* d_in, const int* in_sizes, int n_in,
                              void* d_out, int out_size, void* d_ws, size_t ws_size,
                              hipStream_t stream) {
    const float* h_dec    = (const float*)d_in[0];
    const float* h_enc    = (const float*)d_in[1];
    const int*   src_lens = (const int*)d_in[2];
    const float* W = (const float*)d_in[3];
    const float* b = (const float*)d_in[4];
    const float* v = (const float*)d_in[5];

    float* out = (float*)d_out;
    float* ctx = out;                 // 32*1024
    float* wts = out + 32 * 1024;     // 32*2048

    // workspace layout
    float*    dproj   = (float*)d_ws;                                   // 128 KB
    _Float16* We16    = (_Float16*)((char*)d_ws + 131072);              // 2 MB
    _Float16* h_enc16 = (_Float16*)((char*)d_ws + 2228224);             // 128 MB
    float*    sc      = (float*)((char*)d_ws + 136445952);              // 256 KB
    int*      tbl     = (int*)((char*)d_ws + 136708096);                // 256 KB
    const size_t need_new = 136970240;

    if (ws_size >= need_new) {
        k_pre   <<<25760, 256, 0, stream>>>(h_enc, h_enc16, h_dec, W, b, src_lens,
                                            dproj, We16, sc, ctx, tbl);
        k_score8<<<4096, 256, 0, stream>>>(h_enc16, We16, dproj, v, src_lens, tbl, sc);
        k_ctxsm <<<512, 256, 0, stream>>>(h_enc16, sc, src_lens, wts, ctx);
    } else {
        k_dproj<<<8192, 256, 0, stream>>>(h_dec, W, b, dproj);
        k_score_naive<<<16384, 256, 0, stream>>>(h_enc, W, dproj, v, wts);
        k_softmax<<<32, 256, 0, stream>>>(wts, src_lens);
        k_ctx_naive<<<32, 256, 0, stream>>>(h_enc, wts, ctx);
    }
}

// Round 6
// 481.170 us; speedup vs baseline: 1.1478x; 1.1478x over previous
//
#include <hip/hip_runtime.h>
#include <hip/hip_fp16.h>

#define HS 1024
#define TT 2048

typedef _Float16 half8 __attribute__((ext_vector_type(8)));
typedef float floatx4 __attribute__((ext_vector_type(4)));

// Async global->LDS DMA, 16B per lane. LDS dest = wave-uniform base + lane*16.
__device__ __forceinline__ void dma16(const _Float16* g, _Float16* l) {
    __builtin_amdgcn_global_load_lds(
        (const __attribute__((address_space(1))) unsigned int*)g,
        (__attribute__((address_space(3))) unsigned int*)l, 16, 0, 0);
}

// ---------------- fused pre-pass ---------------------------------------------
// block ranges: [0,16384) cvtA (4-row granularity len skip), [16384,24576)
// dproj, [24576,25600) cvtW, [25600,25664) zero sc, [25664,25696) zero ctx,
// [25696,25760) build row table: tbl[v] = n*TT + t for the v-th valid row in
// n-major concatenation of the first len[n] rows of each n; -1 for v >= S.
__global__ __launch_bounds__(256) void k_pre(const float* __restrict__ h_enc,
                                             _Float16* __restrict__ h_enc16,
                                             const float* __restrict__ h_dec,
                                             const float* __restrict__ W,
                                             const float* __restrict__ bias,
                                             const int* __restrict__ lens,
                                             float* __restrict__ dproj,
                                             _Float16* __restrict__ We16,
                                             float* __restrict__ sc,
                                             float* __restrict__ ctx,
                                             int* __restrict__ tbl) {
    const int b = blockIdx.x;
    const int tid = threadIdx.x;
    if (b < 16384) {
        // cvtA: block covers 4 t-rows of one n; only rows t < len are needed
        // (k_score reads only table rows, k_ctxsm clamps to len).
        const int n = b >> 9;
        const int t4 = (b & 511) * 4;
        if (t4 >= lens[n]) return;
        size_t idx = ((size_t)b * 256 + tid) * 16;
        const float4* g = reinterpret_cast<const float4*>(h_enc + idx);
        _Float16 h[16];
#pragma unroll
        for (int i = 0; i < 4; ++i) {
            float4 f = g[i];
            h[i * 4 + 0] = (_Float16)f.x; h[i * 4 + 1] = (_Float16)f.y;
            h[i * 4 + 2] = (_Float16)f.z; h[i * 4 + 3] = (_Float16)f.w;
        }
        *reinterpret_cast<uint4*>(h_enc16 + idx)     = *reinterpret_cast<uint4*>(&h[0]);
        *reinterpret_cast<uint4*>(h_enc16 + idx + 8) = *reinterpret_cast<uint4*>(&h[8]);
    } else if (b < 24576) {
        // dproj: one wave per (n,a)
        int wid = (b - 16384) * 4 + (tid >> 6);
        int lane = tid & 63;
        int n = wid >> 10, a = wid & 1023;
        const float4* hd = reinterpret_cast<const float4*>(h_dec + (size_t)n * HS);
        const float4* wr = reinterpret_cast<const float4*>(W + (size_t)a * 2048);
        float s = 0.f;
#pragma unroll
        for (int i = 0; i < 4; ++i) {
            float4 h = hd[lane + i * 64];
            float4 w = wr[lane + i * 64];
            s += h.x * w.x + h.y * w.y + h.z * w.z + h.w * w.w;
        }
        for (int off = 32; off; off >>= 1) s += __shfl_xor(s, off);
        if (lane == 0) dproj[wid] = bias[a] + s;
    } else if (b < 25600) {
        // cvtW: We16[a*1024+e] = (fp16) W[a*2048 + 1024 + e]
        int idx4 = ((b - 24576) * 256 + tid) * 4;
        int a = idx4 >> 10;
        int e = idx4 & 1023;
        float4 f = *reinterpret_cast<const float4*>(W + (size_t)a * 2048 + 1024 + e);
        _Float16 h0 = (_Float16)f.x, h1 = (_Float16)f.y, h2 = (_Float16)f.z, h3 = (_Float16)f.w;
        ushort4 p;
        p.x = *(unsigned short*)&h0; p.y = *(unsigned short*)&h1;
        p.z = *(unsigned short*)&h2; p.w = *(unsigned short*)&h3;
        *reinterpret_cast<ushort4*>(We16 + idx4) = p;
    } else if (b < 25664) {
        reinterpret_cast<float4*>(sc)[(b - 25600) * 256 + tid] =
            make_float4(0.f, 0.f, 0.f, 0.f);
    } else if (b < 25696) {
        reinterpret_cast<float4*>(ctx)[(b - 25664) * 256 + tid] =
            make_float4(0.f, 0.f, 0.f, 0.f);
    } else {
        // row table build: 64 blocks x 256 threads x 4 entries = 65536
        const int bi = b - 25696;
        const int v0 = bi * 1024 + tid * 4;
        int vals[4] = {-1, -1, -1, -1};
        int base = 0;
        for (int n = 0; n < 32; ++n) {
            const int ln = lens[n];
#pragma unroll
            for (int k2 = 0; k2 < 4; ++k2) {
                const int vv = v0 + k2;
                if (vv >= base && vv < base + ln) vals[k2] = n * TT + (vv - base);
            }
            base += ln;
        }
        *reinterpret_cast<int4*>(tbl + v0) = make_int4(vals[0], vals[1], vals[2], vals[3]);
    }
}

// K3: flattened fused score GEMM. Virtual-row M dimension (length S = sum(len))
// tiled 128t x 128a, full K=1024 per item. 256 thr = 4 waves (2m x 2n), wave
// 64x64, acc 4x4. LDS: ring-3 of BK=32 K-tiles = 48.5 KB -> 3 blocks/CU.
// Block mapping (r4 lesson): IDENTITY. tile = blockIdx>>3, aT = blockIdx&7.
// Live blocks (tile < Tt) are consecutive blockIdx -> round-robin across all
// 8 XCDs evenly (r4's swizzle concentrated live work on XCDs 0-3: half the
// chip idled, 202 us). The 8 aT-blocks of one A-tile are consecutive -> one
// per XCD (A re-served via L3; HBM is at 2.8%), and each XCD sees a fixed
// aT -> stable B-panel in its L2.
// Counted vmcnt(4): stage(j+1) stays in flight across the per-tile barrier.
// Ring-3 safety: stage(j+2) targets buf (j+2)%3 = (j-1)%3, whose reads all
// completed before this iteration's top barrier. Swizzle (verified
// 0-conflict): granule G -> G ^ ((G>>3)&7) on pre-swizzled global source
// (linear LDS dest) and on ds_read byte offsets.
__global__ __launch_bounds__(256, 3) void k_score8(
        const _Float16* __restrict__ h_enc16, const _Float16* __restrict__ We16,
        const float* __restrict__ dproj, const float* __restrict__ v,
        const int* __restrict__ lens, const int* __restrict__ tbl,
        float* __restrict__ scores) {
    __shared__ _Float16 As[3][128 * 32];   // 3 x 8 KB
    __shared__ _Float16 Bs[3][128 * 32];   // 3 x 8 KB
    __shared__ float s_acc[128];

    const int tid = threadIdx.x;
    const int lane = tid & 63;

    // S = sum(lens): 32 lanes load, 64-lane xor-reduce (uniform across waves)
    int S = (lane < 32) ? lens[lane] : 0;
#pragma unroll
    for (int off = 1; off <= 32; off <<= 1) S += __shfl_xor(S, off);
    const int Tt = (S + 127) >> 7;         // tiles over virtual rows

    const int aT = blockIdx.x & 7, tile = blockIdx.x >> 3;
    if (tile >= Tt) return;                // beyond work list: exit
    const int t0 = tile << 7, a0 = aT << 7;

    if (tid < 128) s_acc[tid] = 0.0f;

    const int w = tid >> 6;
    const int wm = w >> 1, wn = w & 1;     // 2x2 wave grid, wave 64t x 64a
    const int col = lane & 15, quad = lane >> 4;

    // Staging source map: phys granule Gp = c*256+tid (linear LDS dest);
    // logical Gl = Gp ^ ((Gp>>3)&7); row r = Gl>>2 (0..127), granule g = Gl&3.
    // A's global row comes from the flattening table (pads clamp to row 0).
    const _Float16* srcA[2];
    const _Float16* srcB[2];
#pragma unroll
    for (int c = 0; c < 2; ++c) {
        int Gp = c * 256 + tid;
        int Gl = Gp ^ ((Gp >> 3) & 7);
        int r = Gl >> 2, g = Gl & 3;
        int grow = tbl[t0 + r];
        if (grow < 0) grow = 0;
        srcA[c] = h_enc16 + (size_t)grow * HS + g * 8;
        srcB[c] = We16 + ((size_t)(a0 + r)) * HS + g * 8;
    }

    // Pre-swizzled ds_read byte offsets (same involution as the source side).
    int offA[4], offB[4];
#pragma unroll
    for (int mi = 0; mi < 4; ++mi) {
        int r = wm * 64 + mi * 16 + col;
        offA[mi] = (r * 64 + quad * 16) ^ (((r >> 1) & 7) << 4);
    }
#pragma unroll
    for (int ni = 0; ni < 4; ++ni) {
        int r = wn * 64 + ni * 16 + col;
        offB[ni] = (r * 64 + quad * 16) ^ (((r >> 1) & 7) << 4);
    }

    floatx4 acc[4][4];
#pragma unroll
    for (int mi = 0; mi < 4; ++mi)
#pragma unroll
        for (int ni = 0; ni < 4; ++ni) acc[mi][ni] = (floatx4)0.0f;

    auto issue = [&](int kt) {
        const int bb = kt % 3;
#pragma unroll
        for (int c = 0; c < 2; ++c) {
            dma16(srcA[c] + kt * 32, &As[bb][(c * 256 + w * 64) * 8]);
            dma16(srcB[c] + kt * 32, &Bs[bb][(c * 256 + w * 64) * 8]);
        }
    };

    issue(0);
    issue(1);            // 8 loads/thread in flight

    for (int j = 0; j < 31; ++j) {
        // tile j landed when only stage(j+1)'s 4 loads remain outstanding
        asm volatile("s_waitcnt vmcnt(4)" ::: "memory");
        __builtin_amdgcn_s_barrier();
        __builtin_amdgcn_sched_barrier(0);

        const int bb = j % 3;
        const char* Ab = (const char*)As[bb];
        const char* Bb = (const char*)Bs[bb];
        half8 af[4], bf[4];
#pragma unroll
        for (int mi = 0; mi < 4; ++mi)
            af[mi] = *reinterpret_cast<const half8*>(Ab + offA[mi]);
#pragma unroll
        for (int ni = 0; ni < 4; ++ni)
            bf[ni] = *reinterpret_cast<const half8*>(Bb + offB[ni]);
        if (j < 30) issue(j + 2);   // buf (j+2)%3 = (j-1)%3, freed at barrier
        __builtin_amdgcn_s_setprio(1);
#pragma unroll
        for (int mi = 0; mi < 4; ++mi)
#pragma unroll
            for (int ni = 0; ni < 4; ++ni)
                acc[mi][ni] = __builtin_amdgcn_mfma_f32_16x16x32_f16(
                    af[mi], bf[ni], acc[mi][ni], 0, 0, 0);
        __builtin_amdgcn_s_setprio(0);
    }
    {   // final K-tile j = 31
        asm volatile("s_waitcnt vmcnt(0)" ::: "memory");
        __builtin_amdgcn_s_barrier();
        __builtin_amdgcn_sched_barrier(0);
        const char* Ab = (const char*)As[31 % 3];
        const char* Bb = (const char*)Bs[31 % 3];
        half8 af[4], bf[4];
#pragma unroll
        for (int mi = 0; mi < 4; ++mi)
            af[mi] = *reinterpret_cast<const half8*>(Ab + offA[mi]);
#pragma unroll
        for (int ni = 0; ni < 4; ++ni)
            bf[ni] = *reinterpret_cast<const half8*>(Bb + offB[ni]);
        __builtin_amdgcn_s_setprio(1);
#pragma unroll
        for (int mi = 0; mi < 4; ++mi)
#pragma unroll
            for (int ni = 0; ni < 4; ++ni)
                acc[mi][ni] = __builtin_amdgcn_mfma_f32_16x16x32_f16(
                    af[mi], bf[ni], acc[mi][ni], 0, 0, 0);
        __builtin_amdgcn_s_setprio(0);
    }

    // epilogue: s_acc[t] += sum_a v[a]*tanh(C[t][a] + dproj[n(t),a]).
    // C/D layout: col = lane&15 (a), row = quad*4+reg (t). n per row via tbl.
    float vv[4];
#pragma unroll
    for (int ni = 0; ni < 4; ++ni) vv[ni] = v[a0 + wn * 64 + ni * 16 + col];
#pragma unroll
    for (int mi = 0; mi < 4; ++mi) {
#pragma unroll
        for (int rg = 0; rg < 4; ++rg) {
            const int rloc = wm * 64 + mi * 16 + quad * 4 + rg;
            const int rv = tbl[t0 + rloc];
            const int n0 = (rv < 0) ? 0 : (rv >> 11);      // rv = n*2048 + t
            const float* dp = dproj + (size_t)n0 * HS + a0 + wn * 64 + col;
            float s = 0.0f;
#pragma unroll
            for (int ni = 0; ni < 4; ++ni) {
                float x = acc[mi][ni][rg] + dp[ni * 16];
                float e2 = __expf(2.0f * x);
                float th = 1.0f - 2.0f * __builtin_amdgcn_rcpf(e2 + 1.0f);
                s += vv[ni] * th;
            }
            s += __shfl_xor(s, 8);
            s += __shfl_xor(s, 4);
            s += __shfl_xor(s, 2);
            s += __shfl_xor(s, 1);
            if (col == 0) atomicAdd(&s_acc[rloc], s);
        }
    }
    __syncthreads();
    if (tid < 128) {
        const int rv = tbl[t0 + tid];
        if (rv >= 0) atomicAdd(&scores[rv], s_acc[tid]);   // sc pre-zeroed
    }
}

// ---------------- fused softmax + weights write + ctx accumulate -------------
// 512 blocks: n(32) x ec(4) x ts(4). Each block recomputes its row's masked
// (m, sum) from scores (L2-hot); ec==0 blocks write the weights chunk;
// ctx partial accumulated only over t < len.
__global__ __launch_bounds__(256) void k_ctxsm(const _Float16* __restrict__ h_enc16,
                                               const float* __restrict__ sc,
                                               const int* __restrict__ lens,
                                               float* __restrict__ wts,
                                               float* __restrict__ ctx) {
    __shared__ float red[4], red2[4];
    __shared__ float racc[256][8];
    const int b = blockIdx.x;
    const int n = b >> 4, ec = (b >> 2) & 3, ts = b & 3;
    const int tid = threadIdx.x;
    const int len = lens[n];
    const float* srow = sc + (size_t)n * TT;

    float sv[8];
    float m = -3.0e38f;
#pragma unroll
    for (int i = 0; i < 8; ++i) {
        int t = tid + i * 256;
        float s = srow[t];
        s = (t < len) ? s : -1.0e10f;
        sv[i] = s;
        m = fmaxf(m, s);
    }
    for (int off = 1; off <= 32; off <<= 1) m = fmaxf(m, __shfl_xor(m, off));
    if ((tid & 63) == 0) red[tid >> 6] = m;
    __syncthreads();
    m = fmaxf(fmaxf(red[0], red[1]), fmaxf(red[2], red[3]));
    float sum = 0.f;
#pragma unroll
    for (int i = 0; i < 8; ++i) sum += __expf(sv[i] - m);
    for (int off = 1; off <= 32; off <<= 1) sum += __shfl_xor(sum, off);
    if ((tid & 63) == 0) red2[tid >> 6] = sum;
    __syncthreads();
    sum = red2[0] + red2[1] + red2[2] + red2[3];
    const float rinv = 1.0f / sum;

    if (ec == 0) {
#pragma unroll
        for (int j = 0; j < 2; ++j) {
            int t = ts * 512 + j * 256 + tid;
            float s = srow[t];
            s = (t < len) ? s : -1.0e10f;
            wts[(size_t)n * TT + t] = __expf(s - m) * rinv;   // masked -> 0.f
        }
    }

    if (ts * 512 < len) {
        const int tend = min(ts * 512 + 512, len);
        const int q = tid & 31, tg = tid >> 5;
        const int e = ec * 256 + q * 8;
        float acc[8];
#pragma unroll
        for (int j = 0; j < 8; ++j) acc[j] = 0.f;
        for (int t = ts * 512 + tg; t < tend; t += 8) {
            float w = __expf(srow[t] - m) * rinv;
            uint4 raw = *reinterpret_cast<const uint4*>(
                h_enc16 + ((size_t)(n * TT + t)) * HS + e);
            const _Float16* hp = reinterpret_cast<const _Float16*>(&raw);
#pragma unroll
            for (int j = 0; j < 8; ++j) acc[j] += w * (float)hp[j];
        }
#pragma unroll
        for (int j = 0; j < 8; ++j) racc[tid][j] = acc[j];
        __syncthreads();
        if (tid < 32) {
            float s2[8];
#pragma unroll
            for (int j = 0; j < 8; ++j) s2[j] = racc[tid][j];
            for (int g = 1; g < 8; ++g)
#pragma unroll
                for (int j = 0; j < 8; ++j) s2[j] += racc[g * 32 + tid][j];
            float* dst = ctx + (size_t)n * HS + ec * 256 + tid * 8;
#pragma unroll
            for (int j = 0; j < 8; ++j) atomicAdd(dst + j, s2[j]);
        }
    }
}

// ---------- slow-but-correct fallback (only if ws is tiny; unexpected) -------
__global__ __launch_bounds__(256) void k_dproj(const float* __restrict__ h_dec,
                                               const float* __restrict__ W,
                                               const float* __restrict__ bias,
                                               float* __restrict__ dproj) {
    int wid = blockIdx.x * 4 + (threadIdx.x >> 6);
    int lane = threadIdx.x & 63;
    int n = wid >> 10, a = wid & 1023;
    const float4* hd = reinterpret_cast<const float4*>(h_dec + (size_t)n * HS);
    const float4* wr = reinterpret_cast<const float4*>(W + (size_t)a * 2048);
    float s = 0.f;
#pragma unroll
    for (int i = 0; i < 4; ++i) {
        float4 h = hd[lane + i * 64];
        float4 w = wr[lane + i * 64];
        s += h.x * w.x + h.y * w.y + h.z * w.z + h.w * w.w;
    }
    for (int off = 32; off; off >>= 1) s += __shfl_xor(s, off);
    if (lane == 0) dproj[wid] = bias[a] + s;
}

__global__ __launch_bounds__(256) void k_score_naive(const float* __restrict__ h_enc,
                                                     const float* __restrict__ W,
                                                     const float* __restrict__ dproj,
                                                     const float* __restrict__ v,
                                                     float* __restrict__ scores) {
    int gw = blockIdx.x * 4 + (threadIdx.x >> 6);
    int lane = threadIdx.x & 63;
    int n = gw >> 11, t = gw & 2047;
    const float4* he = reinterpret_cast<const float4*>(h_enc + ((size_t)(n * TT + t)) * HS);
    float4 hv[4];
#pragma unroll
    for (int i = 0; i < 4; ++i) hv[i] = he[lane + i * 64];
    float s = 0.f;
    for (int a = 0; a < 1024; ++a) {
        const float4* wr = reinterpret_cast<const float4*>(W + (size_t)a * 2048 + 1024);
        float d = 0.f;
#pragma unroll
        for (int i = 0; i < 4; ++i) {
            float4 wv = wr[lane + i * 64];
            d += hv[i].x * wv.x + hv[i].y * wv.y + hv[i].z * wv.z + hv[i].w * wv.w;
        }
        for (int off = 32; off; off >>= 1) d += __shfl_xor(d, off);
        s += v[a] * tanhf(d + dproj[n * HS + a]);
    }
    if (lane == 0) scores[(size_t)n * TT + t] = s;
}

__global__ __launch_bounds__(256) void k_softmax(float* __restrict__ wout,
                                                 const int* __restrict__ lens) {
    __shared__ float red[4];
    __shared__ float red2[4];
    int n = blockIdx.x, tid = threadIdx.x;
    int len = lens[n];
    float* row = wout + (size_t)n * TT;
    float sv[8];
    float m = -3.0e38f;
#pragma unroll
    for (int i = 0; i < 8; ++i) {
        int t = tid + i * 256;
        float s = row[t];
        s = (t < len) ? s : -1.0e10f;
        sv[i] = s;
        m = fmaxf(m, s);
    }
    for (int off = 1; off <= 32; off <<= 1) m = fmaxf(m, __shfl_xor(m, off));
    if ((tid & 63) == 0) red[tid >> 6] = m;
    __syncthreads();
    m = fmaxf(fmaxf(red[0], red[1]), fmaxf(red[2], red[3]));
    float sum = 0.f, es[8];
#pragma unroll
    for (int i = 0; i < 8; ++i) { es[i] = __expf(sv[i] - m); sum += es[i]; }
    for (int off = 1; off <= 32; off <<= 1) sum += __shfl_xor(sum, off);
    if ((tid & 63) == 0) red2[tid >> 6] = sum;
    __syncthreads();
    sum = red2[0] + red2[1] + red2[2] + red2[3];
    float rinv = 1.0f / sum;
#pragma unroll
    for (int i = 0; i < 8; ++i) row[tid + i * 256] = es[i] * rinv;
}

__global__ __launch_bounds__(256) void k_ctx_naive(const float* __restrict__ h_enc,
                                                   const float* __restrict__ wts,
                                                   float* __restrict__ ctx) {
    int n = blockIdx.x;
    int e = threadIdx.x * 4;
    float4 a = make_float4(0.f, 0.f, 0.f, 0.f);
    const float* wrow = wts + (size_t)n * TT;
    for (int t = 0; t < TT; ++t) {
        float w = wrow[t];
        float4 h = *reinterpret_cast<const float4*>(h_enc + ((size_t)(n * TT + t)) * HS + e);
        a.x += w * h.x; a.y += w * h.y; a.z += w * h.z; a.w += w * h.w;
    }
    *reinterpret_cast<float4*>(ctx + (size_t)n * HS + e) = a;
}

extern "C" void kernel_launch(void* const* d_in, const int* in_sizes, int n_in,
                              void* d_out, int out_size, void* d_ws, size_t ws_size,
                              hipStream_t stream) {
    const float* h_dec    = (const float*)d_in[0];
    const float* h_enc    = (const float*)d_in[1];
    const int*   src_lens = (const int*)d_in[2];
    const float* W = (const float*)d_in[3];
    const float* b = (const float*)d_in[4];
    const float* v = (const float*)d_in[5];

    float* out = (float*)d_out;
    float* ctx = out;                 // 32*1024
    float* wts = out + 32 * 1024;     // 32*2048

    // workspace layout
    float*    dproj   = (float*)d_ws;                                   // 128 KB
    _Float16* We16    = (_Float16*)((char*)d_ws + 131072);              // 2 MB
    _Float16* h_enc16 = (_Float16*)((char*)d_ws + 2228224);             // 128 MB
    float*    sc      = (float*)((char*)d_ws + 136445952);              // 256 KB
    int*      tbl     = (int*)((char*)d_ws + 136708096);                // 256 KB
    const size_t need_new = 136970240;

    if (ws_size >= need_new) {
        k_pre   <<<25760, 256, 0, stream>>>(h_enc, h_enc16, h_dec, W, b, src_lens,
                                            dproj, We16, sc, ctx, tbl);
        k_score8<<<4096, 256, 0, stream>>>(h_enc16, We16, dproj, v, src_lens, tbl, sc);
        k_ctxsm <<<512, 256, 0, stream>>>(h_enc16, sc, src_lens, wts, ctx);
    } else {
        k_dproj<<<8192, 256, 0, stream>>>(h_dec, W, b, dproj);
        k_score_naive<<<16384, 256, 0, stream>>>(h_enc, W, dproj, v, wts);
        k_softmax<<<32, 256, 0, stream>>>(wts, src_lens);
        k_ctx_naive<<<32, 256, 0, stream>>>(h_enc, wts, ctx);
    }
}